// Round 1
// 243.426 us; speedup vs baseline: 1.0261x; 1.0261x over previous
//
#include <hip/hip_runtime.h>

#define EPS_F 1e-5f
#define SCALE_F 0.02f

using short8  = __attribute__((ext_vector_type(8))) short;
using floatx4 = __attribute__((ext_vector_type(4))) float;

__device__ __forceinline__ unsigned short f2bf(float f) {
  unsigned u = __float_as_uint(f);
  return (unsigned short)((u + 0x7fffu + ((u >> 16) & 1u)) >> 16);
}

// ---------------- prep kernel 1: weights + BN coefficients ----------------
// Gather form: 1 thread = one 16B output group (off, c8, co) -> 8 bf16 signs.
__global__ void prep_w(const float* __restrict__ w1, const float* __restrict__ w2,
                       unsigned short* __restrict__ ap1, unsigned short* __restrict__ ap2,
                       const float* g1, const float* b1, const float* m1, const float* v1,
                       const float* g2, const float* b2, const float* m2, const float* v2,
                       float* bnp) {
  const float* __restrict__ w = blockIdx.y ? w2 : w1;
  unsigned short* __restrict__ ap = blockIdx.y ? ap2 : ap1;
  int t = blockIdx.x * 256 + threadIdx.x;   // 73728 groups per tensor
  int off = t >> 13;
  int c8  = (t >> 8) & 31;
  int co  = t & 255;
  const float* ws = w + (size_t)(co * 256 + c8 * 8) * 9 + off;
  short8 o;
#pragma unroll
  for (int j = 0; j < 8; ++j) {
    float v = ws[j * 9];
    o[j] = (v > 0.f) ? (short)0x3F80 : ((v < 0.f) ? (short)0xBF80 : (short)0);
  }
  *(short8*)(ap + (size_t)t * 8) = o;
  if (blockIdx.x == 0 && blockIdx.y == 0) {
    int c = threadIdx.x;
    float i1 = g1[c] * rsqrtf(v1[c] + EPS_F);
    bnp[c]       = SCALE_F * i1;
    bnp[256 + c] = b1[c] - m1[c] * i1;
    float i2 = g2[c] * rsqrtf(v2[c] + EPS_F);
    bnp[512 + c] = SCALE_F * i2;
    bnp[768 + c] = b2[c] - m2[c] * i2;
  }
}

// ---------------- prep kernel 2: x -> padded NHWC bf16 + border zeroing ------
__global__ void prep_x(const float* __restrict__ x, unsigned short* __restrict__ xb,
                       unsigned short* __restrict__ abuf) {
  int h = blockIdx.x;                // 0..27
  int n = blockIdx.y;
  int tid = threadIdx.x;             // = ci
  const float* xs = x + ((size_t)n * 256 + tid) * 784 + h * 28;
  unsigned short* xd = xb + ((size_t)n * 900 + (h + 1) * 30 + 1) * 256 + tid;
#pragma unroll
  for (int p4 = 0; p4 < 7; ++p4) {
    floatx4 f = *(const floatx4*)(xs + p4 * 4);
#pragma unroll
    for (int k = 0; k < 4; ++k)
      xd[(size_t)(p4 * 4 + k) * 256] = f2bf(f[k]);
  }
  // side borders of padded row h+1, both buffers: 2 sides * 64 c4 * 2 bufs
  {
    int bufi = tid >> 7, side = (tid >> 6) & 1, c4 = tid & 63;
    unsigned short* bb = (bufi ? abuf : xb) + ((size_t)n * 900 + (h + 1) * 30 + side * 29) * 256;
    ushort4 z = {0, 0, 0, 0};
    *(ushort4*)(bb + c4 * 4) = z;
  }
  // top/bottom padded rows
  if (h == 0 || h == 27) {
    int row = (h == 0) ? 0 : 29;
    for (int u = tid; u < 3840; u += 256) {    // 2 bufs * 30px * 64 c4
      int bufi = u / 1920;
      int r    = u - bufi * 1920;
      int px   = r >> 6, c4 = r & 63;
      unsigned short* bb = (bufi ? abuf : xb) + ((size_t)n * 900 + row * 30 + px) * 256;
      ushort4 z = {0, 0, 0, 0};
      *(ushort4*)(bb + c4 * 4) = z;
    }
  }
}

// ---------------- staging helpers (ci-block halo tile, 1440 x 16B units) -----
__device__ __forceinline__ void stage_load(const unsigned short* __restrict__ bsrc,
                                           int cb, int tid, short8* stg) {
  const unsigned short* __restrict__ b = bsrc + cb * 64;
#pragma unroll
  for (int i = 0; i < 5; ++i) {
    int u = tid + i * 256;
    int px = u >> 3, c = u & 7;
    stg[i] = *(const short8*)(b + (size_t)px * 256 + c * 8);
  }
  if (tid < 160) {
    int u = tid + 1280;
    int px = u >> 3, c = u & 7;
    stg[5] = *(const short8*)(b + (size_t)px * 256 + c * 8);
  }
}

__device__ __forceinline__ void stage_write(unsigned short* __restrict__ B,
                                            int tid, const short8* stg) {
#pragma unroll
  for (int i = 0; i < 5; ++i) {
    int u = tid + i * 256;
    int px = u >> 3, c = u & 7;
    *(short8*)&B[(px << 6) + ((c ^ (px & 7)) << 3)] = stg[i];
  }
  if (tid < 160) {
    int u = tid + 1280;
    int px = u >> 3, c = u & 7;
    *(short8*)&B[(px << 6) + ((c ^ (px & 7)) << 3)] = stg[5];
  }
}

// ---------------- conv (implicit GEMM, halo-tiled) ----------------
// Block: 256 thr = 4 waves. Macro-tile: 256 co x 112 sp (4 rows) of one image.
// ci-block 64: LDS halo 6 rows x 30 px, XOR-swizzled pitch-64, DOUBLE-buffered.
// T14 async-STAGE: next ci-block's global loads issue before this block's
// MFMA burst; swizzled ds_writes land after; ONE barrier per ci-block.
template<int STAGE>
__global__ __launch_bounds__(256, 2) void bconv(
    const unsigned short* __restrict__ Bin,
    const unsigned short* __restrict__ Apack,
    const float* __restrict__ bnp,
    unsigned short* __restrict__ aout,
    const float* __restrict__ xres,
    float* __restrict__ out)
{
  // stage 1: 29568 ushorts (epilogue C tile) >= 2*11520 (double buffer).
  // stage 2: 23040 ushorts = double buffer.
  __shared__ __align__(16) unsigned short smem[STAGE == 1 ? 29568 : 23040];

  const int tid  = threadIdx.x;
  const int lane = tid & 63;
  const int wv   = tid >> 6;
  const int quad = lane >> 4;
  const int l16  = lane & 15;
  const int spBlk = blockIdx.x;   // 0..6
  const int n     = blockIdx.y;

  const int prow0 = 4 * spBlk;
  const unsigned short* bsrc = Bin + ((size_t)n * 900 + prow0 * 30) * 256;
  const int coW = wv * 64;

  int pxS[7];
#pragma unroll
  for (int s = 0; s < 7; ++s) {
    int lm = s * 16 + l16;
    int hl = lm / 28;
    int w  = lm - hl * 28;
    pxS[s] = hl * 30 + w;
  }

  floatx4 acc[4][7];
#pragma unroll
  for (int c = 0; c < 4; ++c)
#pragma unroll
    for (int s = 0; s < 7; ++s)
      acc[c][s] = (floatx4){0.f, 0.f, 0.f, 0.f};

  short8 stg[6];

  // prologue: stage ci-block 0 into buffer 0
  stage_load(bsrc, 0, tid, stg);
  stage_write(smem, tid, stg);
  __syncthreads();

#pragma unroll 1
  for (int cb = 0; cb < 4; ++cb) {
    unsigned short* Blds = smem + (cb & 1) * 11520;

    // issue next ci-block's global loads NOW; latency hides under the MFMAs
    if (cb < 3) stage_load(bsrc, cb + 1, tid, stg);

    const int cq = cb * 8 + quad;
#pragma unroll 1
    for (int kh = 0; kh < 3; ++kh) {
#pragma unroll
      for (int kw = 0; kw < 3; ++kw) {
        const int D = kh * 30 + kw;
        const int chunk0 = (kh * 3 + kw) * 32 + cq;
#pragma unroll
        for (int half = 0; half < 2; ++half) {
          const int chunk = chunk0 + half * 4;
          const unsigned short* apb = Apack + ((size_t)(chunk * 256 + coW + l16)) * 8;
          short8 a0 = *(const short8*)(apb);
          short8 a1 = *(const short8*)(apb + 16 * 8);
          short8 a2 = *(const short8*)(apb + 32 * 8);
          short8 a3 = *(const short8*)(apb + 48 * 8);
          const int C = half * 4 + quad;
          __builtin_amdgcn_s_setprio(1);
#pragma unroll
          for (int s = 0; s < 7; ++s) {
            int pe = pxS[s] + D;
            short8 b = *(const short8*)&Blds[(pe << 6) + ((C ^ (pe & 7)) << 3)];
            acc[0][s] = __builtin_amdgcn_mfma_f32_16x16x32_bf16(a0, b, acc[0][s], 0, 0, 0);
            acc[1][s] = __builtin_amdgcn_mfma_f32_16x16x32_bf16(a1, b, acc[1][s], 0, 0, 0);
            acc[2][s] = __builtin_amdgcn_mfma_f32_16x16x32_bf16(a2, b, acc[2][s], 0, 0, 0);
            acc[3][s] = __builtin_amdgcn_mfma_f32_16x16x32_bf16(a3, b, acc[3][s], 0, 0, 0);
          }
          __builtin_amdgcn_s_setprio(0);
        }
      }
    }

    // write-late: swizzled LDS writes into the OTHER buffer, one barrier
    if (cb < 3) {
      stage_write(smem + ((cb + 1) & 1) * 11520, tid, stg);
      __syncthreads();
    }
  }

  // Epilogue. C/D layout: col(sp)=l16, row(co within 16-tile)=quad*4+reg.
  if (STAGE == 1) {
    // BN+ReLU -> LDS[px][co] (pitch 264), then coalesced row copies to NHWC.
    __syncthreads();   // last cb's Blds reads done before overwrite
#pragma unroll
    for (int c = 0; c < 4; ++c) {
      int co = coW + c * 16 + quad * 4;
      floatx4 As = *(const floatx4*)(bnp + co);
      floatx4 Bs = *(const floatx4*)(bnp + 256 + co);
#pragma unroll
      for (int s = 0; s < 7; ++s) {
        int px = s * 16 + l16;
        ushort4 o;
        o.x = f2bf(fmaxf(acc[c][s][0] * As[0] + Bs[0], 0.f));
        o.y = f2bf(fmaxf(acc[c][s][1] * As[1] + Bs[1], 0.f));
        o.z = f2bf(fmaxf(acc[c][s][2] * As[2] + Bs[2], 0.f));
        o.w = f2bf(fmaxf(acc[c][s][3] * As[3] + Bs[3], 0.f));
        *(ushort4*)&smem[px * 264 + co] = o;
      }
    }
    __syncthreads();
    unsigned short* dst0 = aout + ((size_t)n * 900 + (prow0 + 1) * 30 + 1) * 256;
    for (int u = tid; u < 3584; u += 256) {   // 112 px * 32 groups of 8 co
      int px = u >> 5;
      int c8 = (u & 31) * 8;
      int r  = px / 28;
      int w  = px - r * 28;
      *(short8*)(dst0 + (size_t)(r * 30 + w) * 256 + c8) = *(const short8*)&smem[px * 264 + c8];
    }
  } else {
#pragma unroll
    for (int c = 0; c < 4; ++c) {
      int co = coW + c * 16 + quad * 4;
      floatx4 As = *(const floatx4*)(bnp + 512 + co);
      floatx4 Bs = *(const floatx4*)(bnp + 768 + co);
#pragma unroll
      for (int s = 0; s < 7; ++s) {
        int m = spBlk * 112 + s * 16 + l16;
#pragma unroll
        for (int r = 0; r < 4; ++r) {
          size_t oidx = ((size_t)n * 256 + co + r) * 784 + m;
          float v = acc[c][s][r] * As[r] + Bs[r] + xres[oidx];
          out[oidx] = fmaxf(v, 0.f);
        }
      }
    }
  }
}

// ---------------- launch ----------------

extern "C" void kernel_launch(void* const* d_in, const int* in_sizes, int n_in,
                              void* d_out, int out_size, void* d_ws, size_t ws_size,
                              hipStream_t stream) {
  const float* x  = (const float*)d_in[0];
  const float* w1 = (const float*)d_in[1];
  const float* g1 = (const float*)d_in[2];
  const float* b1 = (const float*)d_in[3];
  const float* m1 = (const float*)d_in[4];
  const float* v1 = (const float*)d_in[5];
  const float* w2 = (const float*)d_in[6];
  const float* g2 = (const float*)d_in[7];
  const float* b2 = (const float*)d_in[8];
  const float* m2 = (const float*)d_in[9];
  const float* v2 = (const float*)d_in[10];
  float* out = (float*)d_out;

  char* ws = (char*)d_ws;
  const size_t PADBUF = (size_t)64 * 900 * 256 * 2;   // 29,491,200 B
  const size_t WPACK  = 589824ull * 2;                 // 1,179,648 B
  unsigned short* xb   = (unsigned short*)ws;
  unsigned short* abuf = (unsigned short*)(ws + PADBUF);
  unsigned short* ap1  = (unsigned short*)(ws + 2 * PADBUF);
  unsigned short* ap2  = (unsigned short*)(ws + 2 * PADBUF + WPACK);
  float* bnp           = (float*)(ws + 2 * PADBUF + 2 * WPACK);

  prep_w<<<dim3(288, 2), 256, 0, stream>>>(w1, w2, ap1, ap2,
                                           g1, b1, m1, v1, g2, b2, m2, v2, bnp);
  prep_x<<<dim3(28, 64), 256, 0, stream>>>(x, xb, abuf);

  dim3 grid(7, 64);   // sp-tile, image
  bconv<1><<<grid, 256, 0, stream>>>(xb,   ap1, bnp, abuf, nullptr, nullptr);
  bconv<2><<<grid, 256, 0, stream>>>(abuf, ap2, bnp, nullptr, x, out);
}

// Round 3
// 230.678 us; speedup vs baseline: 1.0828x; 1.0553x over previous
//
#include <hip/hip_runtime.h>

#define EPS_F 1e-5f
#define SCALE_F 0.02f

using short8  = __attribute__((ext_vector_type(8))) short;
using floatx4 = __attribute__((ext_vector_type(4))) float;

__device__ __forceinline__ unsigned short f2bf(float f) {
  unsigned u = __float_as_uint(f);
  return (unsigned short)((u + 0x7fffu + ((u >> 16) & 1u)) >> 16);
}

// ---------------- prep kernel 1: weights + BN coefficients ----------------
__global__ void prep_w(const float* __restrict__ w1, const float* __restrict__ w2,
                       unsigned short* __restrict__ ap1, unsigned short* __restrict__ ap2,
                       const float* g1, const float* b1, const float* m1, const float* v1,
                       const float* g2, const float* b2, const float* m2, const float* v2,
                       float* bnp) {
  const float* __restrict__ w = blockIdx.y ? w2 : w1;
  unsigned short* __restrict__ ap = blockIdx.y ? ap2 : ap1;
  int t = blockIdx.x * 256 + threadIdx.x;   // 73728 groups per tensor
  int off = t >> 13;
  int c8  = (t >> 8) & 31;
  int co  = t & 255;
  const float* ws = w + (size_t)(co * 256 + c8 * 8) * 9 + off;
  short8 o;
#pragma unroll
  for (int j = 0; j < 8; ++j) {
    float v = ws[j * 9];
    o[j] = (v > 0.f) ? (short)0x3F80 : ((v < 0.f) ? (short)0xBF80 : (short)0);
  }
  *(short8*)(ap + (size_t)t * 8) = o;
  if (blockIdx.x == 0 && blockIdx.y == 0) {
    int c = threadIdx.x;
    float i1 = g1[c] * rsqrtf(v1[c] + EPS_F);
    bnp[c]       = SCALE_F * i1;
    bnp[256 + c] = b1[c] - m1[c] * i1;
    float i2 = g2[c] * rsqrtf(v2[c] + EPS_F);
    bnp[512 + c] = SCALE_F * i2;
    bnp[768 + c] = b2[c] - m2[c] * i2;
  }
}

// ---------------- prep kernel 2: x -> padded NHWC bf16 + border zeroing ------
__global__ void prep_x(const float* __restrict__ x, unsigned short* __restrict__ xb,
                       unsigned short* __restrict__ abuf) {
  int h = blockIdx.x;                // 0..27
  int n = blockIdx.y;
  int tid = threadIdx.x;             // = ci
  const float* xs = x + ((size_t)n * 256 + tid) * 784 + h * 28;
  unsigned short* xd = xb + ((size_t)n * 900 + (h + 1) * 30 + 1) * 256 + tid;
#pragma unroll
  for (int p4 = 0; p4 < 7; ++p4) {
    floatx4 f = *(const floatx4*)(xs + p4 * 4);
#pragma unroll
    for (int k = 0; k < 4; ++k)
      xd[(size_t)(p4 * 4 + k) * 256] = f2bf(f[k]);
  }
  // side borders of padded row h+1, both buffers
  {
    int bufi = tid >> 7, side = (tid >> 6) & 1, c4 = tid & 63;
    unsigned short* bb = (bufi ? abuf : xb) + ((size_t)n * 900 + (h + 1) * 30 + side * 29) * 256;
    ushort4 z = {0, 0, 0, 0};
    *(ushort4*)(bb + c4 * 4) = z;
  }
  // top/bottom padded rows
  if (h == 0 || h == 27) {
    int row = (h == 0) ? 0 : 29;
    for (int u = tid; u < 3840; u += 256) {
      int bufi = u / 1920;
      int r    = u - bufi * 1920;
      int px   = r >> 6, c4 = r & 63;
      unsigned short* bb = (bufi ? abuf : xb) + ((size_t)n * 900 + row * 30 + px) * 256;
      ushort4 z = {0, 0, 0, 0};
      *(ushort4*)(bb + c4 * 4) = z;
    }
  }
}

// ---------------- conv (implicit GEMM, halo-tiled) ----------------
// Block: 256 thr = 4 waves. Macro-tile: 256 co x 112 sp (4 rows) of one image.
// ci-block 64: LDS halo 6 rows x 30 px, XOR-swizzled pitch-64, double-buffered.
// Staging via global_load_lds: LDS dest is LINEAR, the global SOURCE address
// carries the inverse swizzle (c = slot ^ (px&7)); the swizzled read side is
// unchanged (involution). A/B weight fragments are software-pipelined one
// half-tap ahead; next-cb tap0 pair issues pre-barrier (drained for free).
template<int STAGE>
__global__ __launch_bounds__(256, 2) void bconv(
    const unsigned short* __restrict__ Bin,
    const unsigned short* __restrict__ Apack,
    const float* __restrict__ bnp,
    unsigned short* __restrict__ aout,
    const float* __restrict__ xres,
    float* __restrict__ out)
{
  // stage 1: 29568 ushorts (epilogue C tile) >= 2*12288 (double buffer w/ pad)
  // stage 2: 24576 ushorts = double buffer (12288 each, 1536 units incl. pad)
  __shared__ __align__(16) unsigned short smem[STAGE == 1 ? 29568 : 24576];

  const int tid  = threadIdx.x;
  const int lane = tid & 63;
  const int wv   = tid >> 6;
  const int quad = lane >> 4;
  const int l16  = lane & 15;

  // XCD-aware swizzle: 448 blocks = 8 XCDs x 56. All 7 sp-tiles of an image
  // land on one XCD -> halo rows + stage1->stage2 activations hit its L2.
  int flat = blockIdx.y * 7 + blockIdx.x;
  int idx  = (flat & 7) * 56 + (flat >> 3);
  const int n     = idx / 7;
  const int spBlk = idx - n * 7;

  const int prow0 = 4 * spBlk;
  const unsigned short* bsrc = Bin + ((size_t)n * 900 + prow0 * 30) * 256;
  const int coW = wv * 64;

  int pxS[7];
#pragma unroll
  for (int s = 0; s < 7; ++s) {
    int lm = s * 16 + l16;
    int hl = lm / 28;
    int w  = lm - hl * 28;
    pxS[s] = hl * 30 + w;
  }

  // staging source offsets (elements), inverse-swizzled per lane.
  // unit v = r*256 + tid; px = v>>3 (clamped into halo), slot = v&7,
  // source ci-chunk c = slot ^ (px&7). Pad units [1440,1536) load a clamped
  // (valid) address and land in the never-read LDS pad.
  int goff0, goff1, goff2, goff3, goff4, goff5;
  {
#define MKGOFF(dst, r) { int v = (r) * 256 + tid; int px = v >> 3; \
    if (px > 179) px = 179; int c = (v & 7) ^ (px & 7); dst = px * 256 + c * 8; }
    MKGOFF(goff0, 0) MKGOFF(goff1, 1) MKGOFF(goff2, 2)
    MKGOFF(goff3, 3) MKGOFF(goff4, 4) MKGOFF(goff5, 5)
#undef MKGOFF
  }

#define STAGE_CB(cbi, bufsel) { \
  unsigned short* lb = smem + (bufsel) * 12288 + wv * 512; \
  const unsigned short* gb = bsrc + (cbi) * 64; \
  __builtin_amdgcn_global_load_lds((const __attribute__((address_space(1))) void*)(gb + goff0), \
      (__attribute__((address_space(3))) void*)(lb + 0 * 2048), 16, 0, 0); \
  __builtin_amdgcn_global_load_lds((const __attribute__((address_space(1))) void*)(gb + goff1), \
      (__attribute__((address_space(3))) void*)(lb + 1 * 2048), 16, 0, 0); \
  __builtin_amdgcn_global_load_lds((const __attribute__((address_space(1))) void*)(gb + goff2), \
      (__attribute__((address_space(3))) void*)(lb + 2 * 2048), 16, 0, 0); \
  __builtin_amdgcn_global_load_lds((const __attribute__((address_space(1))) void*)(gb + goff3), \
      (__attribute__((address_space(3))) void*)(lb + 3 * 2048), 16, 0, 0); \
  __builtin_amdgcn_global_load_lds((const __attribute__((address_space(1))) void*)(gb + goff4), \
      (__attribute__((address_space(3))) void*)(lb + 4 * 2048), 16, 0, 0); \
  __builtin_amdgcn_global_load_lds((const __attribute__((address_space(1))) void*)(gb + goff5), \
      (__attribute__((address_space(3))) void*)(lb + 5 * 2048), 16, 0, 0); }

#define LOADA(d0, d1, d2, d3, t, half, CQ8) { \
  const unsigned short* p = Apack + ((size_t)(((t) * 32 + (CQ8) + (half) * 4) * 256 + coW + l16)) * 8; \
  d0 = *(const short8*)p; \
  d1 = *(const short8*)(p + 128); \
  d2 = *(const short8*)(p + 256); \
  d3 = *(const short8*)(p + 384); }

#define HALFMMA(a0, a1, a2, a3, Cx, Dv) { \
  __builtin_amdgcn_s_setprio(1); \
  _Pragma("unroll") \
  for (int s = 0; s < 7; ++s) { \
    int pe = pxS[s] + (Dv); \
    short8 b = *(const short8*)&Blds[(pe << 6) + (((Cx) ^ (pe & 7)) << 3)]; \
    acc[0][s] = __builtin_amdgcn_mfma_f32_16x16x32_bf16(a0, b, acc[0][s], 0, 0, 0); \
    acc[1][s] = __builtin_amdgcn_mfma_f32_16x16x32_bf16(a1, b, acc[1][s], 0, 0, 0); \
    acc[2][s] = __builtin_amdgcn_mfma_f32_16x16x32_bf16(a2, b, acc[2][s], 0, 0, 0); \
    acc[3][s] = __builtin_amdgcn_mfma_f32_16x16x32_bf16(a3, b, acc[3][s], 0, 0, 0); \
  } \
  __builtin_amdgcn_s_setprio(0); }

  floatx4 acc[4][7];
#pragma unroll
  for (int c = 0; c < 4; ++c)
#pragma unroll
    for (int s = 0; s < 7; ++s)
      acc[c][s] = (floatx4){0.f, 0.f, 0.f, 0.f};

  short8 A0, A1, A2, A3, N0, N1, N2, N3;

  // prologue: async-stage ci-block 0 into buffer 0; preload tap0 A-pair.
  // the barrier's implicit vmcnt(0) drain makes these arrive for free.
  STAGE_CB(0, 0);
  LOADA(A0, A1, A2, A3, 0, 0, quad);
  LOADA(N0, N1, N2, N3, 0, 1, quad);
  __syncthreads();

#pragma unroll 1
  for (int cb = 0; cb < 4; ++cb) {
    unsigned short* Blds = smem + (cb & 1) * 12288;
    if (cb < 3) STAGE_CB(cb + 1, (cb + 1) & 1);   // fire-and-forget into other buf
    const int cq8 = cb * 8 + quad;
    int D = 0;
#pragma unroll 1
    for (int t = 0; t < 9; ++t) {
      HALFMMA(A0, A1, A2, A3, quad, D);           // uses (t, half0), loaded >=1 half ago
      if (t < 8) LOADA(A0, A1, A2, A3, t + 1, 0, cq8);
      HALFMMA(N0, N1, N2, N3, 4 + quad, D);       // uses (t, half1)
      if (t < 8) LOADA(N0, N1, N2, N3, t + 1, 1, cq8);
      D += (t == 2 || t == 5) ? 28 : 1;
    }
    if (cb < 3) {
      LOADA(A0, A1, A2, A3, 0, 0, cq8 + 8);       // next cb tap0, pre-barrier (free)
      LOADA(N0, N1, N2, N3, 0, 1, cq8 + 8);
      __syncthreads();
    }
  }

  // Epilogue. C/D layout: col(sp)=l16, row(co within 16-tile)=quad*4+reg.
  if (STAGE == 1) {
    __syncthreads();   // last cb's Blds reads done before overwrite
#pragma unroll
    for (int c = 0; c < 4; ++c) {
      int co = coW + c * 16 + quad * 4;
      floatx4 As = *(const floatx4*)(bnp + co);
      floatx4 Bs = *(const floatx4*)(bnp + 256 + co);
#pragma unroll
      for (int s = 0; s < 7; ++s) {
        int px = s * 16 + l16;
        ushort4 o;
        o.x = f2bf(fmaxf(acc[c][s][0] * As[0] + Bs[0], 0.f));
        o.y = f2bf(fmaxf(acc[c][s][1] * As[1] + Bs[1], 0.f));
        o.z = f2bf(fmaxf(acc[c][s][2] * As[2] + Bs[2], 0.f));
        o.w = f2bf(fmaxf(acc[c][s][3] * As[3] + Bs[3], 0.f));
        *(ushort4*)&smem[px * 264 + co] = o;
      }
    }
    __syncthreads();
    unsigned short* dst0 = aout + ((size_t)n * 900 + (prow0 + 1) * 30 + 1) * 256;
    for (int u = tid; u < 3584; u += 256) {   // 112 px * 32 groups of 8 co
      int px = u >> 5;
      int c8 = (u & 31) * 8;
      int r  = px / 28;
      int w  = px - r * 28;
      *(short8*)(dst0 + (size_t)(r * 30 + w) * 256 + c8) = *(const short8*)&smem[px * 264 + c8];
    }
  } else {
#pragma unroll
    for (int c = 0; c < 4; ++c) {
      int co = coW + c * 16 + quad * 4;
      floatx4 As = *(const floatx4*)(bnp + 512 + co);
      floatx4 Bs = *(const floatx4*)(bnp + 768 + co);
#pragma unroll
      for (int s = 0; s < 7; ++s) {
        int m = spBlk * 112 + s * 16 + l16;
#pragma unroll
        for (int r = 0; r < 4; ++r) {
          size_t oidx = ((size_t)n * 256 + co + r) * 784 + m;
          float v = acc[c][s][r] * As[r] + Bs[r] + xres[oidx];
          out[oidx] = fmaxf(v, 0.f);
        }
      }
    }
  }
#undef STAGE_CB
#undef LOADA
#undef HALFMMA
}

// ---------------- launch ----------------

extern "C" void kernel_launch(void* const* d_in, const int* in_sizes, int n_in,
                              void* d_out, int out_size, void* d_ws, size_t ws_size,
                              hipStream_t stream) {
  const float* x  = (const float*)d_in[0];
  const float* w1 = (const float*)d_in[1];
  const float* g1 = (const float*)d_in[2];
  const float* b1 = (const float*)d_in[3];
  const float* m1 = (const float*)d_in[4];
  const float* v1 = (const float*)d_in[5];
  const float* w2 = (const float*)d_in[6];
  const float* g2 = (const float*)d_in[7];
  const float* b2 = (const float*)d_in[8];
  const float* m2 = (const float*)d_in[9];
  const float* v2 = (const float*)d_in[10];
  float* out = (float*)d_out;

  char* ws = (char*)d_ws;
  const size_t PADBUF = (size_t)64 * 900 * 256 * 2;   // 29,491,200 B
  const size_t WPACK  = 589824ull * 2;                 // 1,179,648 B
  unsigned short* xb   = (unsigned short*)ws;
  unsigned short* abuf = (unsigned short*)(ws + PADBUF);
  unsigned short* ap1  = (unsigned short*)(ws + 2 * PADBUF);
  unsigned short* ap2  = (unsigned short*)(ws + 2 * PADBUF + WPACK);
  float* bnp           = (float*)(ws + 2 * PADBUF + 2 * WPACK);

  prep_w<<<dim3(288, 2), 256, 0, stream>>>(w1, w2, ap1, ap2,
                                           g1, b1, m1, v1, g2, b2, m2, v2, bnp);
  prep_x<<<dim3(28, 64), 256, 0, stream>>>(x, xb, abuf);

  dim3 grid(7, 64);   // sp-tile, image
  bconv<1><<<grid, 256, 0, stream>>>(xb,   ap1, bnp, abuf, nullptr, nullptr);
  bconv<2><<<grid, 256, 0, stream>>>(abuf, ap2, bnp, nullptr, x, out);
}